// Round 7
// baseline (127.186 us; speedup 1.0000x reference)
//
#include <hip/hip_runtime.h>
#include <hip/hip_bf16.h>
#include <math.h>

#define S_DIM 2048
#define B_DIM 64
#define H_DIM 1024
#define KP     8                    // k-split factor for the v GEMM
#define KCHUNK (H_DIM / KP)         // 128 k-rows per chunk
#define BLK_B  4                    // b's per block in v_partial

typedef float f32x4 __attribute__((ext_vector_type(4)));

// ---------------------------------------------------------------------------
// Kernel 1: partial[p,b,h] = sum_{k in chunk p} hidden[b,k] * W[k,h]
// Grid (KP, B/BLK_B) = (8,16) = 128 blocks. Each block serves BLK_B=4 b's from
// one W-row read. hidden slice staged in LDS (broadcast reads).
// Bias is dropped everywhere: hidden.bias is a constant shift per row b and
// cancels in softmax.
// ---------------------------------------------------------------------------
__global__ __launch_bounds__(256) void v_partial_kernel(
    const float* __restrict__ hidden,   // [B,H]
    const float* __restrict__ W,        // [H,H]
    float* __restrict__ partial)        // [KP,B,H]
{
    const int p   = blockIdx.x;
    const int b0  = blockIdx.y * BLK_B;
    const int tid = threadIdx.x;
    const int h0  = tid * 4;
    const int k0  = p * KCHUNK;

    __shared__ float s_hid[BLK_B][KCHUNK];
#pragma unroll
    for (int r = 0; r < (BLK_B * KCHUNK) / 256; ++r) {
        const int i  = tid + r * 256;
        const int bb = i / KCHUNK;
        const int kk = i % KCHUNK;
        s_hid[bb][kk] = hidden[(size_t)(b0 + bb) * H_DIM + k0 + kk];
    }
    __syncthreads();

    f32x4 acc[BLK_B];
#pragma unroll
    for (int bb = 0; bb < BLK_B; ++bb) acc[bb] = (f32x4)0.f;

#pragma unroll 4
    for (int k = 0; k < KCHUNK; ++k) {
        const f32x4 w = *reinterpret_cast<const f32x4*>(W + (size_t)(k0 + k) * H_DIM + h0);
#pragma unroll
        for (int bb = 0; bb < BLK_B; ++bb) {
            const float hk = s_hid[bb][k];
            acc[bb].x = fmaf(hk, w.x, acc[bb].x);
            acc[bb].y = fmaf(hk, w.y, acc[bb].y);
            acc[bb].z = fmaf(hk, w.z, acc[bb].z);
            acc[bb].w = fmaf(hk, w.w, acc[bb].w);
        }
    }

#pragma unroll
    for (int bb = 0; bb < BLK_B; ++bb)
        *reinterpret_cast<f32x4*>(partial + ((size_t)p * B_DIM + b0 + bb) * H_DIM + h0) = acc[bb];
}

// ---------------------------------------------------------------------------
// Kernel 2: v[b,h] = sum_p partial[p,b,h]
// (Separate launch on purpose — round-6 showed folding this into the scores
// kernel costs +5.8 µs: 2048 blocks × serial L3-latency preamble > 1 launch.)
// ---------------------------------------------------------------------------
__global__ __launch_bounds__(256) void v_reduce_kernel(
    const float* __restrict__ partial,  // [KP,B,H]
    float* __restrict__ v)              // [B,H]
{
    const int b   = blockIdx.x;
    const int tid = threadIdx.x;
    const int h0  = tid * 4;

    f32x4 s = (f32x4)0.f;
#pragma unroll
    for (int p = 0; p < KP; ++p)
        s += *reinterpret_cast<const f32x4*>(partial + ((size_t)p * B_DIM + b) * H_DIM + h0);
    *reinterpret_cast<f32x4*>(v + (size_t)b * H_DIM + h0) = s;
}

// ---------------------------------------------------------------------------
// Kernel 3: scores[b,s] = dot(v[b,:], enc[s,b,:])
// Grid (S/64, B) = (32,64), 256 threads = 4 waves, 16 s per wave in pairs
// (8 x 16B loads in flight). PLAIN loads (no nt): enc is re-streamed every
// graph replay and half-fits in the 256 MB L3 — round-4 FETCH showed ~50%
// L3 retention; evict-first nt hints work against that.
// NO fences, NO semaphores (round-4 lesson: device-scope coherence = 7x).
// ---------------------------------------------------------------------------
__global__ __launch_bounds__(256) void scores_kernel(
    const float* __restrict__ enc,      // [S,B,H]
    const float* __restrict__ v,        // [B,H]
    float* __restrict__ scores)         // [B,S]
{
    const int b      = blockIdx.y;
    const int wave   = threadIdx.x >> 6;
    const int lane   = threadIdx.x & 63;
    const int s_base = blockIdx.x * 64 + wave * 16;

    const float* vb = v + (size_t)b * H_DIM;
    const int o = lane * 4;
    const f32x4 v0 = *reinterpret_cast<const f32x4*>(vb + o);
    const f32x4 v1 = *reinterpret_cast<const f32x4*>(vb + o + 256);
    const f32x4 v2 = *reinterpret_cast<const f32x4*>(vb + o + 512);
    const f32x4 v3 = *reinterpret_cast<const f32x4*>(vb + o + 768);

#pragma unroll 2
    for (int i = 0; i < 16; i += 2) {
        const float* ea = enc + ((size_t)(s_base + i) * B_DIM + b) * H_DIM;
        const float* eb = ea + (size_t)B_DIM * H_DIM;   // next s row

        const f32x4 a0 = *reinterpret_cast<const f32x4*>(ea + o);
        const f32x4 a1 = *reinterpret_cast<const f32x4*>(ea + o + 256);
        const f32x4 a2 = *reinterpret_cast<const f32x4*>(ea + o + 512);
        const f32x4 a3 = *reinterpret_cast<const f32x4*>(ea + o + 768);
        const f32x4 b0 = *reinterpret_cast<const f32x4*>(eb + o);
        const f32x4 b1 = *reinterpret_cast<const f32x4*>(eb + o + 256);
        const f32x4 b2 = *reinterpret_cast<const f32x4*>(eb + o + 512);
        const f32x4 b3 = *reinterpret_cast<const f32x4*>(eb + o + 768);

        float acc_a = v0.x * a0.x + v0.y * a0.y + v0.z * a0.z + v0.w * a0.w
                    + v1.x * a1.x + v1.y * a1.y + v1.z * a1.z + v1.w * a1.w
                    + v2.x * a2.x + v2.y * a2.y + v2.z * a2.z + v2.w * a2.w
                    + v3.x * a3.x + v3.y * a3.y + v3.z * a3.z + v3.w * a3.w;
        float acc_b = v0.x * b0.x + v0.y * b0.y + v0.z * b0.z + v0.w * b0.w
                    + v1.x * b1.x + v1.y * b1.y + v1.z * b1.z + v1.w * b1.w
                    + v2.x * b2.x + v2.y * b2.y + v2.z * b2.z + v2.w * b2.w
                    + v3.x * b3.x + v3.y * b3.y + v3.z * b3.z + v3.w * b3.w;

#pragma unroll
        for (int off = 32; off > 0; off >>= 1) {
            acc_a += __shfl_xor(acc_a, off);
            acc_b += __shfl_xor(acc_b, off);
        }

        if (lane == 0) {
            scores[(size_t)b * S_DIM + s_base + i]     = acc_a;
            scores[(size_t)b * S_DIM + s_base + i + 1] = acc_b;
        }
    }
}

// ---------------------------------------------------------------------------
// Kernel 4: out[b,0,s] = softmax over s of scores[b,:]
// One block per b; f32x4 vectorized row access (8 floats/thread).
// ---------------------------------------------------------------------------
__global__ __launch_bounds__(256) void softmax_kernel(
    const float* __restrict__ scores,   // [B,S]
    float* __restrict__ out)            // [B,1,S]
{
    const int b   = blockIdx.x;
    const int tid = threadIdx.x;
    const float* row = scores + (size_t)b * S_DIM;

    f32x4 va = *reinterpret_cast<const f32x4*>(row + tid * 8);
    f32x4 vb = *reinterpret_cast<const f32x4*>(row + tid * 8 + 4);

    float m = fmaxf(fmaxf(fmaxf(va.x, va.y), fmaxf(va.z, va.w)),
                    fmaxf(fmaxf(vb.x, vb.y), fmaxf(vb.z, vb.w)));

    __shared__ float red[256];
    red[tid] = m;
    __syncthreads();
    for (int off = 128; off > 0; off >>= 1) {
        if (tid < off) red[tid] = fmaxf(red[tid], red[tid + off]);
        __syncthreads();
    }
    m = red[0];
    __syncthreads();

    va.x = __expf(va.x - m); va.y = __expf(va.y - m);
    va.z = __expf(va.z - m); va.w = __expf(va.w - m);
    vb.x = __expf(vb.x - m); vb.y = __expf(vb.y - m);
    vb.z = __expf(vb.z - m); vb.w = __expf(vb.w - m);
    const float sum = va.x + va.y + va.z + va.w + vb.x + vb.y + vb.z + vb.w;

    red[tid] = sum;
    __syncthreads();
    for (int off = 128; off > 0; off >>= 1) {
        if (tid < off) red[tid] += red[tid + off];
        __syncthreads();
    }
    const float inv = 1.0f / red[0];
    __syncthreads();

    va *= inv;
    vb *= inv;
    *reinterpret_cast<f32x4*>(out + (size_t)b * S_DIM + tid * 8)     = va;
    *reinterpret_cast<f32x4*>(out + (size_t)b * S_DIM + tid * 8 + 4) = vb;
}

// ---------------------------------------------------------------------------
extern "C" void kernel_launch(void* const* d_in, const int* in_sizes, int n_in,
                              void* d_out, int out_size, void* d_ws, size_t ws_size,
                              hipStream_t stream) {
    const float* hidden = (const float*)d_in[0];   // [1,B,H]
    const float* enc    = (const float*)d_in[1];   // [S,B,H]
    const float* W      = (const float*)d_in[2];   // [H,H]
    // d_in[3] = bias: unused — constant per-row shift cancels in softmax.
    float* out          = (float*)d_out;           // [B,1,S]

    float* ws      = (float*)d_ws;
    float* partial = ws;                                    // KP*B*H (2 MB)
    float* v       = partial + (size_t)KP * B_DIM * H_DIM;  // B*H (256 KB)
    float* scores  = v + (size_t)B_DIM * H_DIM;             // B*S (512 KB)

    v_partial_kernel<<<dim3(KP, B_DIM / BLK_B), dim3(256), 0, stream>>>(hidden, W, partial);
    v_reduce_kernel<<<dim3(B_DIM), dim3(256), 0, stream>>>(partial, v);
    scores_kernel<<<dim3(S_DIM / 64, B_DIM), dim3(256), 0, stream>>>(enc, v, scores);
    softmax_kernel<<<dim3(B_DIM), dim3(256), 0, stream>>>(scores, out);
}

// Round 8
// 100.983 us; speedup vs baseline: 1.2595x; 1.2595x over previous
//
#include <hip/hip_runtime.h>
#include <hip/hip_bf16.h>
#include <math.h>

#define S_DIM 2048
#define B_DIM 64
#define H_DIM 1024
#define KP     16                   // k-split factor for the v GEMM (fills all 256 CUs)
#define KCHUNK (H_DIM / KP)         // 64 k-rows per chunk
#define BLK_B  4                    // b's per block in v_partial

typedef float f32x4 __attribute__((ext_vector_type(4)));

// ---------------------------------------------------------------------------
// Kernel 1: partial[p,b,h] = sum_{k in chunk p} hidden[b,k] * W[k,h]
// Grid (KP, B/BLK_B) = (16,16) = 256 blocks -> one per CU. Each block serves
// BLK_B=4 b's from one W-row read (W logical traffic stays 64 MB).
// Bias is dropped everywhere: constant shift per row b cancels in softmax.
// ---------------------------------------------------------------------------
__global__ __launch_bounds__(256) void v_partial_kernel(
    const float* __restrict__ hidden,   // [B,H]
    const float* __restrict__ W,        // [H,H]
    float* __restrict__ partial)        // [KP,B,H]
{
    const int p   = blockIdx.x;
    const int b0  = blockIdx.y * BLK_B;
    const int tid = threadIdx.x;
    const int h0  = tid * 4;
    const int k0  = p * KCHUNK;

    __shared__ float s_hid[BLK_B][KCHUNK];
    {
        // BLK_B*KCHUNK = 256 -> each thread loads exactly one element
        const int bb = tid / KCHUNK;
        const int kk = tid % KCHUNK;
        s_hid[bb][kk] = hidden[(size_t)(b0 + bb) * H_DIM + k0 + kk];
    }
    __syncthreads();

    f32x4 acc[BLK_B];
#pragma unroll
    for (int bb = 0; bb < BLK_B; ++bb) acc[bb] = (f32x4)0.f;

#pragma unroll 4
    for (int k = 0; k < KCHUNK; ++k) {
        const f32x4 w = *reinterpret_cast<const f32x4*>(W + (size_t)(k0 + k) * H_DIM + h0);
#pragma unroll
        for (int bb = 0; bb < BLK_B; ++bb) {
            const float hk = s_hid[bb][k];
            acc[bb].x = fmaf(hk, w.x, acc[bb].x);
            acc[bb].y = fmaf(hk, w.y, acc[bb].y);
            acc[bb].z = fmaf(hk, w.z, acc[bb].z);
            acc[bb].w = fmaf(hk, w.w, acc[bb].w);
        }
    }

#pragma unroll
    for (int bb = 0; bb < BLK_B; ++bb)
        *reinterpret_cast<f32x4*>(partial + ((size_t)p * B_DIM + b0 + bb) * H_DIM + h0) = acc[bb];
}

// ---------------------------------------------------------------------------
// Kernel 2: v[b,h] = sum_p partial[p,b,h]
// (Separate launch on purpose — round-6 showed folding this into the scores
// kernel costs +5.8 µs: 2048 blocks × serial L3-latency preamble > 1 launch.)
// ---------------------------------------------------------------------------
__global__ __launch_bounds__(256) void v_reduce_kernel(
    const float* __restrict__ partial,  // [KP,B,H]
    float* __restrict__ v)              // [B,H]
{
    const int b   = blockIdx.x;
    const int tid = threadIdx.x;
    const int h0  = tid * 4;

    f32x4 s = (f32x4)0.f;
#pragma unroll
    for (int p = 0; p < KP; ++p)
        s += *reinterpret_cast<const f32x4*>(partial + ((size_t)p * B_DIM + b) * H_DIM + h0);
    *reinterpret_cast<f32x4*>(v + (size_t)b * H_DIM + h0) = s;
}

// ---------------------------------------------------------------------------
// Kernel 3: scores[b,s] = dot(v[b,:], enc[s,b,:])
// Grid (S/64, B) = (32,64), 256 threads = 4 waves, 16 s per wave in batches
// of 4 (16 x 16B nt loads in flight, 4 independent acc chains).
// NT loads on enc are REQUIRED: round-7 measured removing them = +24.5 µs
// (plain loads thrash L2; nt protects L2 while L3 retains ~half of enc).
// NO fences, NO semaphores (round-4 lesson: device-scope coherence = 7x).
// ---------------------------------------------------------------------------
__global__ __launch_bounds__(256) void scores_kernel(
    const float* __restrict__ enc,      // [S,B,H]
    const float* __restrict__ v,        // [B,H]
    float* __restrict__ scores)         // [B,S]
{
    const int b      = blockIdx.y;
    const int wave   = threadIdx.x >> 6;
    const int lane   = threadIdx.x & 63;
    const int s_base = blockIdx.x * 64 + wave * 16;

    const float* vb = v + (size_t)b * H_DIM;
    const int o = lane * 4;
    const f32x4 v0 = *reinterpret_cast<const f32x4*>(vb + o);
    const f32x4 v1 = *reinterpret_cast<const f32x4*>(vb + o + 256);
    const f32x4 v2 = *reinterpret_cast<const f32x4*>(vb + o + 512);
    const f32x4 v3 = *reinterpret_cast<const f32x4*>(vb + o + 768);

    const size_t srow = (size_t)B_DIM * H_DIM;   // stride between s rows

    for (int i = 0; i < 16; i += 4) {
        const float* ra = enc + ((size_t)(s_base + i) * B_DIM + b) * H_DIM;
        const float* rb = ra + srow;
        const float* rc = rb + srow;
        const float* rd = rc + srow;

        const f32x4 a0 = __builtin_nontemporal_load(reinterpret_cast<const f32x4*>(ra + o));
        const f32x4 a1 = __builtin_nontemporal_load(reinterpret_cast<const f32x4*>(ra + o + 256));
        const f32x4 a2 = __builtin_nontemporal_load(reinterpret_cast<const f32x4*>(ra + o + 512));
        const f32x4 a3 = __builtin_nontemporal_load(reinterpret_cast<const f32x4*>(ra + o + 768));
        const f32x4 b0 = __builtin_nontemporal_load(reinterpret_cast<const f32x4*>(rb + o));
        const f32x4 b1 = __builtin_nontemporal_load(reinterpret_cast<const f32x4*>(rb + o + 256));
        const f32x4 b2 = __builtin_nontemporal_load(reinterpret_cast<const f32x4*>(rb + o + 512));
        const f32x4 b3 = __builtin_nontemporal_load(reinterpret_cast<const f32x4*>(rb + o + 768));
        const f32x4 c0 = __builtin_nontemporal_load(reinterpret_cast<const f32x4*>(rc + o));
        const f32x4 c1 = __builtin_nontemporal_load(reinterpret_cast<const f32x4*>(rc + o + 256));
        const f32x4 c2 = __builtin_nontemporal_load(reinterpret_cast<const f32x4*>(rc + o + 512));
        const f32x4 c3 = __builtin_nontemporal_load(reinterpret_cast<const f32x4*>(rc + o + 768));
        const f32x4 d0 = __builtin_nontemporal_load(reinterpret_cast<const f32x4*>(rd + o));
        const f32x4 d1 = __builtin_nontemporal_load(reinterpret_cast<const f32x4*>(rd + o + 256));
        const f32x4 d2 = __builtin_nontemporal_load(reinterpret_cast<const f32x4*>(rd + o + 512));
        const f32x4 d3 = __builtin_nontemporal_load(reinterpret_cast<const f32x4*>(rd + o + 768));

        float acc_a = v0.x * a0.x + v0.y * a0.y + v0.z * a0.z + v0.w * a0.w
                    + v1.x * a1.x + v1.y * a1.y + v1.z * a1.z + v1.w * a1.w
                    + v2.x * a2.x + v2.y * a2.y + v2.z * a2.z + v2.w * a2.w
                    + v3.x * a3.x + v3.y * a3.y + v3.z * a3.z + v3.w * a3.w;
        float acc_b = v0.x * b0.x + v0.y * b0.y + v0.z * b0.z + v0.w * b0.w
                    + v1.x * b1.x + v1.y * b1.y + v1.z * b1.z + v1.w * b1.w
                    + v2.x * b2.x + v2.y * b2.y + v2.z * b2.z + v2.w * b2.w
                    + v3.x * b3.x + v3.y * b3.y + v3.z * b3.z + v3.w * b3.w;
        float acc_c = v0.x * c0.x + v0.y * c0.y + v0.z * c0.z + v0.w * c0.w
                    + v1.x * c1.x + v1.y * c1.y + v1.z * c1.z + v1.w * c1.w
                    + v2.x * c2.x + v2.y * c2.y + v2.z * c2.z + v2.w * c2.w
                    + v3.x * c3.x + v3.y * c3.y + v3.z * c3.z + v3.w * c3.w;
        float acc_d = v0.x * d0.x + v0.y * d0.y + v0.z * d0.z + v0.w * d0.w
                    + v1.x * d1.x + v1.y * d1.y + v1.z * d1.z + v1.w * d1.w
                    + v2.x * d2.x + v2.y * d2.y + v2.z * d2.z + v2.w * d2.w
                    + v3.x * d3.x + v3.y * d3.y + v3.z * d3.z + v3.w * d3.w;

#pragma unroll
        for (int off = 32; off > 0; off >>= 1) {
            acc_a += __shfl_xor(acc_a, off);
            acc_b += __shfl_xor(acc_b, off);
            acc_c += __shfl_xor(acc_c, off);
            acc_d += __shfl_xor(acc_d, off);
        }

        if (lane == 0) {
            float* sp = scores + (size_t)b * S_DIM + s_base + i;
            sp[0] = acc_a;
            sp[1] = acc_b;
            sp[2] = acc_c;
            sp[3] = acc_d;
        }
    }
}

// ---------------------------------------------------------------------------
// Kernel 4: out[b,0,s] = softmax over s of scores[b,:]
// One block per b; f32x4 vectorized row access (8 floats/thread).
// ---------------------------------------------------------------------------
__global__ __launch_bounds__(256) void softmax_kernel(
    const float* __restrict__ scores,   // [B,S]
    float* __restrict__ out)            // [B,1,S]
{
    const int b   = blockIdx.x;
    const int tid = threadIdx.x;
    const float* row = scores + (size_t)b * S_DIM;

    f32x4 va = *reinterpret_cast<const f32x4*>(row + tid * 8);
    f32x4 vb = *reinterpret_cast<const f32x4*>(row + tid * 8 + 4);

    float m = fmaxf(fmaxf(fmaxf(va.x, va.y), fmaxf(va.z, va.w)),
                    fmaxf(fmaxf(vb.x, vb.y), fmaxf(vb.z, vb.w)));

    __shared__ float red[256];
    red[tid] = m;
    __syncthreads();
    for (int off = 128; off > 0; off >>= 1) {
        if (tid < off) red[tid] = fmaxf(red[tid], red[tid + off]);
        __syncthreads();
    }
    m = red[0];
    __syncthreads();

    va.x = __expf(va.x - m); va.y = __expf(va.y - m);
    va.z = __expf(va.z - m); va.w = __expf(va.w - m);
    vb.x = __expf(vb.x - m); vb.y = __expf(vb.y - m);
    vb.z = __expf(vb.z - m); vb.w = __expf(vb.w - m);
    const float sum = va.x + va.y + va.z + va.w + vb.x + vb.y + vb.z + vb.w;

    red[tid] = sum;
    __syncthreads();
    for (int off = 128; off > 0; off >>= 1) {
        if (tid < off) red[tid] += red[tid + off];
        __syncthreads();
    }
    const float inv = 1.0f / red[0];
    __syncthreads();

    va *= inv;
    vb *= inv;
    *reinterpret_cast<f32x4*>(out + (size_t)b * S_DIM + tid * 8)     = va;
    *reinterpret_cast<f32x4*>(out + (size_t)b * S_DIM + tid * 8 + 4) = vb;
}

// ---------------------------------------------------------------------------
extern "C" void kernel_launch(void* const* d_in, const int* in_sizes, int n_in,
                              void* d_out, int out_size, void* d_ws, size_t ws_size,
                              hipStream_t stream) {
    const float* hidden = (const float*)d_in[0];   // [1,B,H]
    const float* enc    = (const float*)d_in[1];   // [S,B,H]
    const float* W      = (const float*)d_in[2];   // [H,H]
    // d_in[3] = bias: unused — constant per-row shift cancels in softmax.
    float* out          = (float*)d_out;           // [B,1,S]

    float* ws      = (float*)d_ws;
    float* partial = ws;                                    // KP*B*H (4 MB)
    float* v       = partial + (size_t)KP * B_DIM * H_DIM;  // B*H (256 KB)
    float* scores  = v + (size_t)B_DIM * H_DIM;             // B*S (512 KB)

    v_partial_kernel<<<dim3(KP, B_DIM / BLK_B), dim3(256), 0, stream>>>(hidden, W, partial);
    v_reduce_kernel<<<dim3(B_DIM), dim3(256), 0, stream>>>(partial, v);
    scores_kernel<<<dim3(S_DIM / 64, B_DIM), dim3(256), 0, stream>>>(enc, v, scores);
    softmax_kernel<<<dim3(B_DIM), dim3(256), 0, stream>>>(scores, out);
}

// Round 9
// 97.972 us; speedup vs baseline: 1.2982x; 1.0307x over previous
//
#include <hip/hip_runtime.h>
#include <hip/hip_bf16.h>
#include <math.h>

#define S_DIM 2048
#define B_DIM 64
#define H_DIM 1024
#define HC     64                   // h-columns per v-block (one per lane)
#define BLK_B  4                    // b's per v-block

typedef float f32x4 __attribute__((ext_vector_type(4)));

// ---------------------------------------------------------------------------
// Kernel 1: v[b,h] = sum_k hidden[b,k] * W[k,h]  — h-SPLIT, single kernel.
// Grid (H/HC, B/BLK_B) = (16,16) = 256 blocks x 512 threads (1 block/CU).
// Each block owns 64 columns x 4 b's and the FULL k range -> no cross-block
// reduction (replaces round-8's v_partial + v_reduce pair: one less dispatch,
// one less gap, no 4 MB partial round-trip). W traffic unchanged: 64 MB,
// L2/L3-resident on replay. 8 waves each own a k-eighth; lane l owns column
// h0+l -> per iter one coalesced 256 B W load + broadcast ds_read_b128 of
// transposed hidden + 4 FMA. Intra-block LDS reduce over waves.
// Bias dropped everywhere: constant shift per row b cancels in softmax.
// ---------------------------------------------------------------------------
__global__ __launch_bounds__(512) void v_kernel(
    const float* __restrict__ hidden,   // [B,H]
    const float* __restrict__ W,        // [H,H]
    float* __restrict__ v)              // [B,H]
{
    const int h0   = blockIdx.x * HC;
    const int b0   = blockIdx.y * BLK_B;
    const int tid  = threadIdx.x;
    const int wave = tid >> 6;          // 0..7
    const int lane = tid & 63;
    const int h    = h0 + lane;

    __shared__ float s_hidT[H_DIM][BLK_B];   // transposed: [k][bb], 16 KB
    {
        // 512 threads x 8 floats = 4096 = BLK_B*H
        const int i  = tid * 8;
        const int bb = i >> 10;              // i / H_DIM
        const int kk = i & (H_DIM - 1);
        const f32x4 lo = *reinterpret_cast<const f32x4*>(hidden + (size_t)(b0 + bb) * H_DIM + kk);
        const f32x4 hi = *reinterpret_cast<const f32x4*>(hidden + (size_t)(b0 + bb) * H_DIM + kk + 4);
        s_hidT[kk + 0][bb] = lo.x; s_hidT[kk + 1][bb] = lo.y;
        s_hidT[kk + 2][bb] = lo.z; s_hidT[kk + 3][bb] = lo.w;
        s_hidT[kk + 4][bb] = hi.x; s_hidT[kk + 5][bb] = hi.y;
        s_hidT[kk + 6][bb] = hi.z; s_hidT[kk + 7][bb] = hi.w;
    }
    __syncthreads();

    const int k0 = wave * (H_DIM / 8);       // 128-k chunk per wave
    f32x4 acc = (f32x4)0.f;                  // acc[bb] for this lane's column
#pragma unroll 8
    for (int k = 0; k < H_DIM / 8; ++k) {
        const float w  = W[(size_t)(k0 + k) * H_DIM + h];          // 256B/wave coalesced
        const f32x4 hv = *reinterpret_cast<const f32x4*>(&s_hidT[k0 + k][0]); // broadcast
        acc.x = fmaf(hv.x, w, acc.x);
        acc.y = fmaf(hv.y, w, acc.y);
        acc.z = fmaf(hv.z, w, acc.z);
        acc.w = fmaf(hv.w, w, acc.w);
    }

    __shared__ float red[8][BLK_B][HC];      // 8 KB
    red[wave][0][lane] = acc.x;
    red[wave][1][lane] = acc.y;
    red[wave][2][lane] = acc.z;
    red[wave][3][lane] = acc.w;
    __syncthreads();

    if (tid < BLK_B * HC) {                  // 256 threads finalize
        const int bb = tid >> 6;
        const int l  = tid & 63;
        float s = 0.f;
#pragma unroll
        for (int w2 = 0; w2 < 8; ++w2) s += red[w2][bb][l];
        v[(size_t)(b0 + bb) * H_DIM + h0 + l] = s;
    }
}

// ---------------------------------------------------------------------------
// Kernel 2: scores[b,s] = dot(v[b,:], enc[s,b,:])
// Grid (S/64, B) = (32,64), 256 threads = 4 waves, 16 s per wave in batches
// of 4 (16 x 16B nt loads in flight, 4 independent acc chains).
// NT loads on enc are REQUIRED: round-7 measured removing them = +24.5 µs
// (plain loads thrash L2; nt protects L2 while L3 retains ~half of enc).
// NO fences, NO semaphores (round-4 lesson: device-scope coherence = 7x).
// ---------------------------------------------------------------------------
__global__ __launch_bounds__(256) void scores_kernel(
    const float* __restrict__ enc,      // [S,B,H]
    const float* __restrict__ v,        // [B,H]
    float* __restrict__ scores)         // [B,S]
{
    const int b      = blockIdx.y;
    const int wave   = threadIdx.x >> 6;
    const int lane   = threadIdx.x & 63;
    const int s_base = blockIdx.x * 64 + wave * 16;

    const float* vb = v + (size_t)b * H_DIM;
    const int o = lane * 4;
    const f32x4 v0 = *reinterpret_cast<const f32x4*>(vb + o);
    const f32x4 v1 = *reinterpret_cast<const f32x4*>(vb + o + 256);
    const f32x4 v2 = *reinterpret_cast<const f32x4*>(vb + o + 512);
    const f32x4 v3 = *reinterpret_cast<const f32x4*>(vb + o + 768);

    const size_t srow = (size_t)B_DIM * H_DIM;   // stride between s rows

    for (int i = 0; i < 16; i += 4) {
        const float* ra = enc + ((size_t)(s_base + i) * B_DIM + b) * H_DIM;
        const float* rb = ra + srow;
        const float* rc = rb + srow;
        const float* rd = rc + srow;

        const f32x4 a0 = __builtin_nontemporal_load(reinterpret_cast<const f32x4*>(ra + o));
        const f32x4 a1 = __builtin_nontemporal_load(reinterpret_cast<const f32x4*>(ra + o + 256));
        const f32x4 a2 = __builtin_nontemporal_load(reinterpret_cast<const f32x4*>(ra + o + 512));
        const f32x4 a3 = __builtin_nontemporal_load(reinterpret_cast<const f32x4*>(ra + o + 768));
        const f32x4 b0 = __builtin_nontemporal_load(reinterpret_cast<const f32x4*>(rb + o));
        const f32x4 b1 = __builtin_nontemporal_load(reinterpret_cast<const f32x4*>(rb + o + 256));
        const f32x4 b2 = __builtin_nontemporal_load(reinterpret_cast<const f32x4*>(rb + o + 512));
        const f32x4 b3 = __builtin_nontemporal_load(reinterpret_cast<const f32x4*>(rb + o + 768));
        const f32x4 c0 = __builtin_nontemporal_load(reinterpret_cast<const f32x4*>(rc + o));
        const f32x4 c1 = __builtin_nontemporal_load(reinterpret_cast<const f32x4*>(rc + o + 256));
        const f32x4 c2 = __builtin_nontemporal_load(reinterpret_cast<const f32x4*>(rc + o + 512));
        const f32x4 c3 = __builtin_nontemporal_load(reinterpret_cast<const f32x4*>(rc + o + 768));
        const f32x4 d0 = __builtin_nontemporal_load(reinterpret_cast<const f32x4*>(rd + o));
        const f32x4 d1 = __builtin_nontemporal_load(reinterpret_cast<const f32x4*>(rd + o + 256));
        const f32x4 d2 = __builtin_nontemporal_load(reinterpret_cast<const f32x4*>(rd + o + 512));
        const f32x4 d3 = __builtin_nontemporal_load(reinterpret_cast<const f32x4*>(rd + o + 768));

        float acc_a = v0.x * a0.x + v0.y * a0.y + v0.z * a0.z + v0.w * a0.w
                    + v1.x * a1.x + v1.y * a1.y + v1.z * a1.z + v1.w * a1.w
                    + v2.x * a2.x + v2.y * a2.y + v2.z * a2.z + v2.w * a2.w
                    + v3.x * a3.x + v3.y * a3.y + v3.z * a3.z + v3.w * a3.w;
        float acc_b = v0.x * b0.x + v0.y * b0.y + v0.z * b0.z + v0.w * b0.w
                    + v1.x * b1.x + v1.y * b1.y + v1.z * b1.z + v1.w * b1.w
                    + v2.x * b2.x + v2.y * b2.y + v2.z * b2.z + v2.w * b2.w
                    + v3.x * b3.x + v3.y * b3.y + v3.z * b3.z + v3.w * b3.w;
        float acc_c = v0.x * c0.x + v0.y * c0.y + v0.z * c0.z + v0.w * c0.w
                    + v1.x * c1.x + v1.y * c1.y + v1.z * c1.z + v1.w * c1.w
                    + v2.x * c2.x + v2.y * c2.y + v2.z * c2.z + v2.w * c2.w
                    + v3.x * c3.x + v3.y * c3.y + v3.z * c3.z + v3.w * c3.w;
        float acc_d = v0.x * d0.x + v0.y * d0.y + v0.z * d0.z + v0.w * d0.w
                    + v1.x * d1.x + v1.y * d1.y + v1.z * d1.z + v1.w * d1.w
                    + v2.x * d2.x + v2.y * d2.y + v2.z * d2.z + v2.w * d2.w
                    + v3.x * d3.x + v3.y * d3.y + v3.z * d3.z + v3.w * d3.w;

#pragma unroll
        for (int off = 32; off > 0; off >>= 1) {
            acc_a += __shfl_xor(acc_a, off);
            acc_b += __shfl_xor(acc_b, off);
            acc_c += __shfl_xor(acc_c, off);
            acc_d += __shfl_xor(acc_d, off);
        }

        if (lane == 0) {
            f32x4 r; r.x = acc_a; r.y = acc_b; r.z = acc_c; r.w = acc_d;
            *reinterpret_cast<f32x4*>(scores + (size_t)b * S_DIM + s_base + i) = r;
        }
    }
}

// ---------------------------------------------------------------------------
// Kernel 3: out[b,0,s] = softmax over s of scores[b,:]
// One block per b; f32x4 vectorized row access (8 floats/thread).
// ---------------------------------------------------------------------------
__global__ __launch_bounds__(256) void softmax_kernel(
    const float* __restrict__ scores,   // [B,S]
    float* __restrict__ out)            // [B,1,S]
{
    const int b   = blockIdx.x;
    const int tid = threadIdx.x;
    const float* row = scores + (size_t)b * S_DIM;

    f32x4 va = *reinterpret_cast<const f32x4*>(row + tid * 8);
    f32x4 vb = *reinterpret_cast<const f32x4*>(row + tid * 8 + 4);

    float m = fmaxf(fmaxf(fmaxf(va.x, va.y), fmaxf(va.z, va.w)),
                    fmaxf(fmaxf(vb.x, vb.y), fmaxf(vb.z, vb.w)));

    __shared__ float red[256];
    red[tid] = m;
    __syncthreads();
    for (int off = 128; off > 0; off >>= 1) {
        if (tid < off) red[tid] = fmaxf(red[tid], red[tid + off]);
        __syncthreads();
    }
    m = red[0];
    __syncthreads();

    va.x = __expf(va.x - m); va.y = __expf(va.y - m);
    va.z = __expf(va.z - m); va.w = __expf(va.w - m);
    vb.x = __expf(vb.x - m); vb.y = __expf(vb.y - m);
    vb.z = __expf(vb.z - m); vb.w = __expf(vb.w - m);
    const float sum = va.x + va.y + va.z + va.w + vb.x + vb.y + vb.z + vb.w;

    red[tid] = sum;
    __syncthreads();
    for (int off = 128; off > 0; off >>= 1) {
        if (tid < off) red[tid] += red[tid + off];
        __syncthreads();
    }
    const float inv = 1.0f / red[0];
    __syncthreads();

    va *= inv;
    vb *= inv;
    *reinterpret_cast<f32x4*>(out + (size_t)b * S_DIM + tid * 8)     = va;
    *reinterpret_cast<f32x4*>(out + (size_t)b * S_DIM + tid * 8 + 4) = vb;
}

// ---------------------------------------------------------------------------
extern "C" void kernel_launch(void* const* d_in, const int* in_sizes, int n_in,
                              void* d_out, int out_size, void* d_ws, size_t ws_size,
                              hipStream_t stream) {
    const float* hidden = (const float*)d_in[0];   // [1,B,H]
    const float* enc    = (const float*)d_in[1];   // [S,B,H]
    const float* W      = (const float*)d_in[2];   // [H,H]
    // d_in[3] = bias: unused — constant per-row shift cancels in softmax.
    float* out          = (float*)d_out;           // [B,1,S]

    float* ws     = (float*)d_ws;
    float* v      = ws;                                 // B*H (256 KB)
    float* scores = v + (size_t)B_DIM * H_DIM;          // B*S (512 KB)

    v_kernel<<<dim3(H_DIM / HC, B_DIM / BLK_B), dim3(512), 0, stream>>>(hidden, W, v);
    scores_kernel<<<dim3(S_DIM / 64, B_DIM), dim3(256), 0, stream>>>(enc, v, scores);
    softmax_kernel<<<dim3(B_DIM), dim3(256), 0, stream>>>(scores, out);
}